// Round 16
// baseline (53.157 us; speedup 1.0000x reference)
//
#include <hip/hip_runtime.h>

#define RADIUS 5
#define WIN    11
#define WIN2   121
#define KCLS   6
#define HH     128
#define WW     128
#define BB     4
#define NPIX   (HH*WW)
#define TPB    128                  // 4 lanes per pixel, 32 px per block
#define PXB    32                   // pixels per block
#define NBLK   (BB*HH*(WW/PXB))     // 2048 blocks
#define LABW   (PXB + 2*RADIUS)     // 42 cols
#define NSITE  (WIN*LABW)           // 462 sites
#define PLSTR  (NSITE*2)            // floats per class-pair plane

__global__ __launch_bounds__(TPB, 4) void ncut_fused(
    const float* __restrict__ labels,
    const float* __restrict__ weights,
    float* __restrict__ part,         // [12][NBLK]: slots 0-5 num_k, 6-11 den_k
    unsigned* __restrict__ counter,
    float* __restrict__ out) {
  __shared__ float shl[3 * PLSTR];    // label tile, 2772 floats = 11.1 KB
  __shared__ float shred[2 * 12];
  __shared__ int   lastFlag;

  const int tid = threadIdx.x;
  const int blk = blockIdx.x;
  const int b   = blk >> 9;                 // 512 blocks per image
  const int rem = blk & 511;
  const int y0  = rem >> 2;
  const int x0  = (rem & 3) * PXB;

  // ---- stage zero-padded label tile, class-pair interleaved ----
  const float* labB = labels + (size_t)b * KCLS * NPIX;
  for (int s = tid; s < NSITE; s += TPB) {
    const int tr = s / LABW;
    const int tc = s - tr * LABW;
    const int gy = y0 - RADIUS + tr;
    const int gx = x0 + tc - RADIUS;
    const bool ok = ((unsigned)gy < (unsigned)HH) & ((unsigned)gx < (unsigned)WW);
    const float* lp = labB + (size_t)gy * WW + gx;
#pragma unroll
    for (int p = 0; p < 3; ++p) {
      float2 v = make_float2(0.f, 0.f);
      if (ok) {
        v.x = lp[(size_t)(2 * p) * NPIX];
        v.y = lp[(size_t)(2 * p + 1) * NPIX];
      }
      *reinterpret_cast<float2*>(shl + p * PLSTR + 2 * s) = v;
    }
  }
  __syncthreads();

  // ---- per-thread: pixel px, quad set {4g+q} on the ALIGNED quad grid ----
  const int px = tid >> 2;          // 0..31
  const int q  = tid & 3;           // 0..3
  const size_t pxg = (size_t)b * NPIX + (size_t)y0 * WW + x0 + px;
  const int S  = (int)(pxg & 3);    // row-start misalignment (floats)
  const float* wal = weights + pxg * WIN2 - S;   // 16B-aligned base
  const int T0 = 4 * q - S;         // tap offset of this lane's quads

  float2 a0 = make_float2(0.f, 0.f);
  float2 a1 = make_float2(0.f, 0.f);
  float2 a2 = make_float2(0.f, 0.f);
  float wsum = 0.f;

#pragma unroll
  for (int g = 0; g < 8; ++g) {
    // q==3,g==7 would be quad 31 (OOB, taps all >120): clamp to quad 30
    const int kq = (g == 7) ? ((q == 3) ? 30 : 28 + q) : 4 * g + q;
    const float4 wv = *reinterpret_cast<const float4*>(wal + 4 * kq);
#pragma unroll
    for (int m = 0; m < 4; ++m) {
      float w = (m == 0) ? wv.x : (m == 1) ? wv.y : (m == 2) ? wv.z : wv.w;
      int   t = 16 * g + m + T0;    // tap index (edges: <0 or >120)
      bool valid = true;
      if (g == 0) valid = (q != 0) | (m >= S);             // t >= 0
      if (g == 7) valid = (q < 2) | ((q == 2) & (m <= S)); // t <= 120
      if (!valid) { w = 0.0f; t = 0; }
      const int r  = (t * 5958) >> 16;    // t/11, exact for 0<=t<=123
      const int li = px + t + (LABW - WIN) * r;   // px + row*42 + col
      const float2 v0 = *reinterpret_cast<const float2*>(shl + 2 * li);
      const float2 v1 = *reinterpret_cast<const float2*>(shl + PLSTR + 2 * li);
      const float2 v2 = *reinterpret_cast<const float2*>(shl + 2 * PLSTR + 2 * li);
      wsum += w;
      a0.x += w * v0.x; a0.y += w * v0.y;
      a1.x += w * v1.x; a1.y += w * v1.y;
      a2.x += w * v2.x; a2.y += w * v2.y;
    }
  }

  // ---- reduce the 4 q-lanes (xor 1,2) ----
#pragma unroll
  for (int off = 1; off <= 2; off <<= 1) {
    wsum += __shfl_xor(wsum, off);
    a0.x += __shfl_xor(a0.x, off); a0.y += __shfl_xor(a0.y, off);
    a1.x += __shfl_xor(a1.x, off); a1.y += __shfl_xor(a1.y, off);
    a2.x += __shfl_xor(a2.x, off); a2.y += __shfl_xor(a2.y, off);
  }

  // ---- num/den per pixel (center site = 5*42 + 5) ----
  const int lc = px + 5 * LABW + 5;
  const float2 c0 = *reinterpret_cast<const float2*>(shl + 2 * lc);
  const float2 c1 = *reinterpret_cast<const float2*>(shl + PLSTR + 2 * lc);
  const float2 c2 = *reinterpret_cast<const float2*>(shl + 2 * PLSTR + 2 * lc);
  float nv[KCLS] = {c0.x * a0.x, c0.y * a0.y, c1.x * a1.x,
                    c1.y * a1.y, c2.x * a2.x, c2.y * a2.y};
  float dv[KCLS] = {c0.x * wsum, c0.y * wsum, c1.x * wsum,
                    c1.y * wsum, c2.x * wsum, c2.y * wsum};

  // ---- reduce across the 16 pixels of this wave (lane bits 2..5) ----
#pragma unroll
  for (int off = 4; off <= 32; off <<= 1) {
#pragma unroll
    for (int k = 0; k < KCLS; ++k) {
      nv[k] += __shfl_xor(nv[k], off);
      dv[k] += __shfl_xor(dv[k], off);
    }
  }
  const int wave = tid >> 6;
  if ((tid & 63) == 0) {
#pragma unroll
    for (int k = 0; k < KCLS; ++k) {
      shred[wave * 12 + k]     = nv[k];
      shred[wave * 12 + 6 + k] = dv[k];
    }
  }
  __syncthreads();

  // ---- per-block slot store: relaxed agent-scope (cache-bypass, NO fence) ----
  if (tid < 12) {
    const float s = shred[tid] + shred[12 + tid];
    __hip_atomic_store(part + tid * NBLK + blk, s,
                       __ATOMIC_RELAXED, __HIP_MEMORY_SCOPE_AGENT);
  }
  // __syncthreads drains vmcnt(0): stores have reached the coherence point
  __syncthreads();
  if (tid == 0) {
    unsigned old = __hip_atomic_fetch_add(counter, 1u, __ATOMIC_RELAXED,
                                          __HIP_MEMORY_SCOPE_AGENT);
    lastFlag = (old == NBLK - 1) ? 1 : 0;
  }
  __syncthreads();
  if (!lastFlag) return;

  // ---- last block: reduce part[12][2048] with bypassing loads ----
  // 48 sums (isden*24 + b*6 + k), 2 threads per sum, 256 floats each.
  float s = 0.f;
  const int sumid = tid >> 1;       // 0..63, active < 48
  if (sumid < 48) {
    const int isden = sumid / 24;
    const int bk    = sumid - isden * 24;
    const int fb    = bk / KCLS;
    const int fk    = bk - fb * KCLS;
    const int slot  = isden * KCLS + fk;
    const float* p  = part + (size_t)slot * NBLK + fb * (NBLK / BB)
                      + (tid & 1) * 256;
#pragma unroll 8
    for (int i = 0; i < 256; ++i)
      s += __hip_atomic_load(p + i, __ATOMIC_RELAXED,
                             __HIP_MEMORY_SCOPE_AGENT);
  }
  s += __shfl_xor(s, 1);            // combine the 2 halves
  if (((tid & 1) == 0) && sumid < 48) shl[sumid] = s;
  __syncthreads();
  float val = 0.f;
  if (tid < 24) val = fabsf(shl[tid] / shl[24 + tid]) * (1.0f / BB);
#pragma unroll
  for (int off = 32; off; off >>= 1) val += __shfl_down(val, off);
  if (tid == 0) out[0] = (float)KCLS - val;
}

extern "C" void kernel_launch(void* const* d_in, const int* in_sizes, int n_in,
                              void* d_out, int out_size, void* d_ws, size_t ws_size,
                              hipStream_t stream) {
  const float* labels  = (const float*)d_in[0];
  const float* weights = (const float*)d_in[1];
  float* out = (float*)d_out;
  float*    part    = (float*)d_ws;                        // 12*2048 floats
  unsigned* counter = (unsigned*)((char*)d_ws + 12 * NBLK * 4);

  hipMemsetAsync(counter, 0, 4, stream);                   // zero counter only
  ncut_fused<<<NBLK, TPB, 0, stream>>>(labels, weights, part, counter, out);
}

// Round 17
// 19.087 us; speedup vs baseline: 2.7850x; 2.7850x over previous
//
#include <hip/hip_runtime.h>

#define RADIUS 5
#define WIN    11
#define WIN2   121
#define KCLS   6
#define HH     128
#define WW     128
#define BB     4
#define NPIX   (HH*WW)
#define TPB    128                  // 4 lanes per pixel, 32 px per block
#define PXB    32                   // pixels per block
#define NBLK   (BB*HH*(WW/PXB))     // 2048 blocks
#define LABW   (PXB + 2*RADIUS)     // 42 cols
#define NSITE  (WIN*LABW)           // 462 sites
#define PLSTR  (NSITE*2)            // floats per class-pair plane

__global__ __launch_bounds__(TPB, 4) void ncut_main(
    const float* __restrict__ labels,
    const float* __restrict__ weights,
    float* __restrict__ part) {
  // label tile: 3 pair-planes of [site][2 classes] -> ds_read_b64 per pair
  __shared__ float shl[3 * PLSTR];    // 2772 floats = 11.1 KB
  __shared__ float shred[2 * 12];

  const int tid = threadIdx.x;
  const int blk = blockIdx.x;
  const int b   = blk >> 9;                 // 512 blocks per image
  const int rem = blk & 511;
  const int y0  = rem >> 2;
  const int x0  = (rem & 3) * PXB;

  // ---- stage zero-padded label tile, class-pair interleaved ----
  const float* labB = labels + (size_t)b * KCLS * NPIX;
  for (int s = tid; s < NSITE; s += TPB) {
    const int tr = s / LABW;
    const int tc = s - tr * LABW;
    const int gy = y0 - RADIUS + tr;
    const int gx = x0 + tc - RADIUS;
    const bool ok = ((unsigned)gy < (unsigned)HH) & ((unsigned)gx < (unsigned)WW);
    const float* lp = labB + (size_t)gy * WW + gx;
#pragma unroll
    for (int p = 0; p < 3; ++p) {
      float2 v = make_float2(0.f, 0.f);
      if (ok) {
        v.x = lp[(size_t)(2 * p) * NPIX];
        v.y = lp[(size_t)(2 * p + 1) * NPIX];
      }
      *reinterpret_cast<float2*>(shl + p * PLSTR + 2 * s) = v;
    }
  }
  __syncthreads();

  // ---- per-thread: pixel px, quad set {4g+q} on the ALIGNED quad grid ----
  const int px = tid >> 2;          // 0..31
  const int q  = tid & 3;           // 0..3
  const size_t pxg = (size_t)b * NPIX + (size_t)y0 * WW + x0 + px;
  const int S  = (int)(pxg & 3);    // row-start misalignment (floats)
  const float* wal = weights + pxg * WIN2 - S;   // 16B-aligned base
  const int T0 = 4 * q - S;         // tap offset of this lane's quads

  float2 a0 = make_float2(0.f, 0.f);
  float2 a1 = make_float2(0.f, 0.f);
  float2 a2 = make_float2(0.f, 0.f);
  float wsum = 0.f;

#pragma unroll
  for (int g = 0; g < 8; ++g) {
    // q==3,g==7 would be quad 31 (OOB, taps all >120): clamp to quad 30
    const int kq = (g == 7) ? ((q == 3) ? 30 : 28 + q) : 4 * g + q;
    const float4 wv = *reinterpret_cast<const float4*>(wal + 4 * kq);
#pragma unroll
    for (int m = 0; m < 4; ++m) {
      float w = (m == 0) ? wv.x : (m == 1) ? wv.y : (m == 2) ? wv.z : wv.w;
      int   t = 16 * g + m + T0;    // tap index (edges: <0 or >120)
      bool valid = true;
      if (g == 0) valid = (q != 0) | (m >= S);             // t >= 0
      if (g == 7) valid = (q < 2) | ((q == 2) & (m <= S)); // t <= 120
      if (!valid) { w = 0.0f; t = 0; }
      const int r  = (t * 5958) >> 16;    // t/11, exact for 0<=t<=123
      const int li = px + t + (LABW - WIN) * r;   // px + row*42 + col
      const float2 v0 = *reinterpret_cast<const float2*>(shl + 2 * li);
      const float2 v1 = *reinterpret_cast<const float2*>(shl + PLSTR + 2 * li);
      const float2 v2 = *reinterpret_cast<const float2*>(shl + 2 * PLSTR + 2 * li);
      wsum += w;
      a0.x += w * v0.x; a0.y += w * v0.y;
      a1.x += w * v1.x; a1.y += w * v1.y;
      a2.x += w * v2.x; a2.y += w * v2.y;
    }
  }

  // ---- reduce the 4 q-lanes (xor 1,2) ----
#pragma unroll
  for (int off = 1; off <= 2; off <<= 1) {
    wsum += __shfl_xor(wsum, off);
    a0.x += __shfl_xor(a0.x, off); a0.y += __shfl_xor(a0.y, off);
    a1.x += __shfl_xor(a1.x, off); a1.y += __shfl_xor(a1.y, off);
    a2.x += __shfl_xor(a2.x, off); a2.y += __shfl_xor(a2.y, off);
  }

  // ---- num/den per pixel (center site = 5*42 + 5) ----
  const int lc = px + 5 * LABW + 5;
  const float2 c0 = *reinterpret_cast<const float2*>(shl + 2 * lc);
  const float2 c1 = *reinterpret_cast<const float2*>(shl + PLSTR + 2 * lc);
  const float2 c2 = *reinterpret_cast<const float2*>(shl + 2 * PLSTR + 2 * lc);
  float nv[KCLS] = {c0.x * a0.x, c0.y * a0.y, c1.x * a1.x,
                    c1.y * a1.y, c2.x * a2.x, c2.y * a2.y};
  float dv[KCLS] = {c0.x * wsum, c0.y * wsum, c1.x * wsum,
                    c1.y * wsum, c2.x * wsum, c2.y * wsum};

  // ---- reduce across the 16 pixels of this wave (lane bits 2..5) ----
#pragma unroll
  for (int off = 4; off <= 32; off <<= 1) {
#pragma unroll
    for (int k = 0; k < KCLS; ++k) {
      nv[k] += __shfl_xor(nv[k], off);
      dv[k] += __shfl_xor(dv[k], off);
    }
  }
  const int wave = tid >> 6;
  if ((tid & 63) == 0) {
#pragma unroll
    for (int k = 0; k < KCLS; ++k) {
      shred[wave * 12 + k]     = nv[k];
      shred[wave * 12 + 6 + k] = dv[k];
    }
  }
  __syncthreads();
  // transposed partials: part[slot][NBLK] -> final kernel reads coalesced
  if (tid < 12) {
    part[tid * NBLK + blk] = shred[tid] + shred[12 + tid];
  }
}

// ---- final: L = num/den per (b,k); out = K - (1/B) * sum |L| ----
// 48 sums (isden,b,k) x 4 segments of 128 consecutive floats, coalesced f4.
__global__ __launch_bounds__(256) void ncut_final(
    const float* __restrict__ part, float* __restrict__ out) {
  __shared__ float shf[4 * 48];
  const int t     = threadIdx.x;
  const int sumid = t >> 2;         // 0..63, active < 48
  const int seg   = t & 3;
  if (sumid < 48) {
    const int isden = sumid / 24;
    const int bk    = sumid - isden * 24;
    const int b     = bk / KCLS;
    const int k     = bk - b * KCLS;
    const int slot  = isden * KCLS + k;
    const float* p  = part + (size_t)slot * NBLK + b * (NBLK / BB) + seg * 128;
    float s = 0.f;
#pragma unroll 8
    for (int i = 0; i < 32; ++i) {
      const float4 v = *reinterpret_cast<const float4*>(p + 4 * i);
      s += v.x + v.y + v.z + v.w;
    }
    shf[seg * 48 + sumid] = s;
  }
  __syncthreads();
  float val = 0.f;
  if (t < 24) {
    float num = 0.f, den = 0.f;
#pragma unroll
    for (int sg = 0; sg < 4; ++sg) {
      num += shf[sg * 48 + t];
      den += shf[sg * 48 + 24 + t];
    }
    val = fabsf(num / den) * (1.0f / BB);
  }
  if (t < 64) {
#pragma unroll
    for (int off = 32; off; off >>= 1) val += __shfl_down(val, off);
    if (t == 0) out[0] = (float)KCLS - val;
  }
}

extern "C" void kernel_launch(void* const* d_in, const int* in_sizes, int n_in,
                              void* d_out, int out_size, void* d_ws, size_t ws_size,
                              hipStream_t stream) {
  const float* labels  = (const float*)d_in[0];
  const float* weights = (const float*)d_in[1];
  float* out  = (float*)d_out;
  float* part = (float*)d_ws;      // 12 * 2048 floats = 98304 B

  ncut_main<<<NBLK, TPB, 0, stream>>>(labels, weights, part);
  ncut_final<<<1, 256, 0, stream>>>(part, out);
}

// Round 18
// 18.979 us; speedup vs baseline: 2.8008x; 1.0057x over previous
//
#include <hip/hip_runtime.h>

#define RADIUS 5
#define WIN    11
#define WIN2   121
#define KCLS   6
#define HH     128
#define WW     128
#define BB     4
#define NPIX   (HH*WW)
#define TPB    128                  // 4 lanes per pixel, 32 px per block
#define PXB    32                   // pixels per block
#define NBLK   (BB*HH*(WW/PXB))     // 2048 blocks
#define LABW   (PXB + 2*RADIUS)     // 42 cols
#define NSITE  (WIN*LABW)           // 462 sites

__global__ __launch_bounds__(TPB, 4) void ncut_main(
    const float* __restrict__ labels,
    const float* __restrict__ weights,
    float* __restrict__ part) {
  // label tile: quad plane [site][4] (classes 0-3, b128) + pair plane [site][2]
  __shared__ __align__(16) float shq[NSITE * 4];   // 7392 B
  __shared__ __align__(8)  float shp[NSITE * 2];   // 3696 B
  __shared__ float shred[2 * 12];

  const int tid = threadIdx.x;
  const int blk = blockIdx.x;
  const int b   = blk >> 9;                 // 512 blocks per image
  const int rem = blk & 511;
  const int y0  = rem >> 2;
  const int x0  = (rem & 3) * PXB;

  // ---- stage zero-padded label tile, quad+pair interleaved ----
  const float* labB = labels + (size_t)b * KCLS * NPIX;
  for (int s = tid; s < NSITE; s += TPB) {
    const int tr = s / LABW;
    const int tc = s - tr * LABW;
    const int gy = y0 - RADIUS + tr;
    const int gx = x0 + tc - RADIUS;
    const bool ok = ((unsigned)gy < (unsigned)HH) & ((unsigned)gx < (unsigned)WW);
    const float* lp = labB + (size_t)gy * WW + gx;
    float4 v4 = make_float4(0.f, 0.f, 0.f, 0.f);
    float2 v2 = make_float2(0.f, 0.f);
    if (ok) {
      v4.x = lp[0];
      v4.y = lp[1 * NPIX];
      v4.z = lp[2 * NPIX];
      v4.w = lp[3 * NPIX];
      v2.x = lp[4 * NPIX];
      v2.y = lp[5 * NPIX];
    }
    *reinterpret_cast<float4*>(shq + 4 * s) = v4;
    *reinterpret_cast<float2*>(shp + 2 * s) = v2;
  }
  __syncthreads();

  // ---- per-thread: pixel px, quad set {4g+q} on the ALIGNED quad grid ----
  const int px = tid >> 2;          // 0..31
  const int q  = tid & 3;           // 0..3
  const size_t pxg = (size_t)b * NPIX + (size_t)y0 * WW + x0 + px;
  const int S  = (int)(pxg & 3);    // row-start misalignment (floats)
  const float* wal = weights + pxg * WIN2 - S;   // 16B-aligned base
  const int T0 = 4 * q - S;         // tap offset of this lane's quads

  float a0 = 0.f, a1 = 0.f, a2 = 0.f, a3 = 0.f, a4 = 0.f, a5 = 0.f;
  float wsum = 0.f;

#pragma unroll
  for (int g = 0; g < 8; ++g) {
    // q==3,g==7 would be quad 31 (OOB, taps all >120): clamp to quad 30
    const int kq = (g == 7) ? ((q == 3) ? 30 : 28 + q) : 4 * g + q;
    const float4 wv = *reinterpret_cast<const float4*>(wal + 4 * kq);
#pragma unroll
    for (int m = 0; m < 4; ++m) {
      float w = (m == 0) ? wv.x : (m == 1) ? wv.y : (m == 2) ? wv.z : wv.w;
      int   t = 16 * g + m + T0;    // tap index (edges: <0 or >120)
      bool valid = true;
      if (g == 0) valid = (q != 0) | (m >= S);             // t >= 0
      if (g == 7) valid = (q < 2) | ((q == 2) & (m <= S)); // t <= 120
      if (!valid) { w = 0.0f; t = 0; }
      const int r  = (t * 5958) >> 16;    // t/11, exact for 0<=t<=123
      const int li = px + t + (LABW - WIN) * r;   // px + row*42 + col
      const float4 v03 = *reinterpret_cast<const float4*>(shq + 4 * li);
      const float2 v45 = *reinterpret_cast<const float2*>(shp + 2 * li);
      wsum += w;
      a0 += w * v03.x; a1 += w * v03.y;
      a2 += w * v03.z; a3 += w * v03.w;
      a4 += w * v45.x; a5 += w * v45.y;
    }
  }

  // ---- reduce the 4 q-lanes (xor 1,2) ----
#pragma unroll
  for (int off = 1; off <= 2; off <<= 1) {
    wsum += __shfl_xor(wsum, off);
    a0 += __shfl_xor(a0, off); a1 += __shfl_xor(a1, off);
    a2 += __shfl_xor(a2, off); a3 += __shfl_xor(a3, off);
    a4 += __shfl_xor(a4, off); a5 += __shfl_xor(a5, off);
  }

  // ---- num/den per pixel (center site = 5*42 + 5) ----
  const int lc = px + 5 * LABW + 5;
  const float4 c03 = *reinterpret_cast<const float4*>(shq + 4 * lc);
  const float2 c45 = *reinterpret_cast<const float2*>(shp + 2 * lc);
  const float cp[KCLS] = {c03.x, c03.y, c03.z, c03.w, c45.x, c45.y};
  const float av[KCLS] = {a0, a1, a2, a3, a4, a5};
  float nv[KCLS], dv[KCLS];
#pragma unroll
  for (int k = 0; k < KCLS; ++k) {
    nv[k] = cp[k] * av[k];
    dv[k] = cp[k] * wsum;
  }

  // ---- reduce across the 16 pixels of this wave (lane bits 2..5) ----
#pragma unroll
  for (int off = 4; off <= 32; off <<= 1) {
#pragma unroll
    for (int k = 0; k < KCLS; ++k) {
      nv[k] += __shfl_xor(nv[k], off);
      dv[k] += __shfl_xor(dv[k], off);
    }
  }
  const int wave = tid >> 6;
  if ((tid & 63) == 0) {
#pragma unroll
    for (int k = 0; k < KCLS; ++k) {
      shred[wave * 12 + k]     = nv[k];
      shred[wave * 12 + 6 + k] = dv[k];
    }
  }
  __syncthreads();
  // transposed partials: part[slot][NBLK] -> final kernel reads coalesced
  if (tid < 12) {
    part[tid * NBLK + blk] = shred[tid] + shred[12 + tid];
  }
}

// ---- final: L = num/den per (b,k); out = K - (1/B) * sum |L| ----
// 48 sums (isden,b,k) x 4 segments of 128 consecutive floats, coalesced f4.
__global__ __launch_bounds__(256) void ncut_final(
    const float* __restrict__ part, float* __restrict__ out) {
  __shared__ float shf[4 * 48];
  const int t     = threadIdx.x;
  const int sumid = t >> 2;         // 0..63, active < 48
  const int seg   = t & 3;
  if (sumid < 48) {
    const int isden = sumid / 24;
    const int bk    = sumid - isden * 24;
    const int b     = bk / KCLS;
    const int k     = bk - b * KCLS;
    const int slot  = isden * KCLS + k;
    const float* p  = part + (size_t)slot * NBLK + b * (NBLK / BB) + seg * 128;
    float s = 0.f;
#pragma unroll 8
    for (int i = 0; i < 32; ++i) {
      const float4 v = *reinterpret_cast<const float4*>(p + 4 * i);
      s += v.x + v.y + v.z + v.w;
    }
    shf[seg * 48 + sumid] = s;
  }
  __syncthreads();
  float val = 0.f;
  if (t < 24) {
    float num = 0.f, den = 0.f;
#pragma unroll
    for (int sg = 0; sg < 4; ++sg) {
      num += shf[sg * 48 + t];
      den += shf[sg * 48 + 24 + t];
    }
    val = fabsf(num / den) * (1.0f / BB);
  }
  if (t < 64) {
#pragma unroll
    for (int off = 16; off; off >>= 1) val += __shfl_down(val, off);
    if (t == 0) out[0] = (float)KCLS - val;
  }
}

extern "C" void kernel_launch(void* const* d_in, const int* in_sizes, int n_in,
                              void* d_out, int out_size, void* d_ws, size_t ws_size,
                              hipStream_t stream) {
  const float* labels  = (const float*)d_in[0];
  const float* weights = (const float*)d_in[1];
  float* out  = (float*)d_out;
  float* part = (float*)d_ws;      // 12 * 2048 floats = 98304 B

  ncut_main<<<NBLK, TPB, 0, stream>>>(labels, weights, part);
  ncut_final<<<1, 256, 0, stream>>>(part, out);
}